// Round 7
// baseline (110.010 us; speedup 1.0000x reference)
//
#include <hip/hip_runtime.h>

#define IMH 384
#define IMW 384
#define OH 378
#define OW 378
#define NB 64
#define SROWS 27
#define INROWS 33          // SROWS + 6
#define NSTRIP 14          // 14*27 = 378 EXACTLY -- no masked rows anywhere
#define NBLOCKS (NSTRIP * NB)   // 896 blocks = 3.5 blocks/CU avg
#define BLOCK 256          // 4 waves = 16 DPP groups of 16 lanes
#define GSTRIDE 26         // output cols per group (13 lanes x 2 cols)

// Round 16: exact tiling + DPP-chain strength reduction.
//  - R15 (warmup specialization) WIN: 107.8 -> 106.7. Op-removal is 3-for-3;
//    occupancy levers 0-for-2. Continue removing ops only.
//  - (a) 378 = 27x14: SROWS 24->27, NSTRIP 16->14. Row work per output row
//    30/24=1.25 -> 33/27=1.222 (-2.2%), same for HBM halo bytes; the
//    (y0+r-6)<OH guard and the last-strip dead rows vanish. 896 blocks =
//    3.5/CU avg; safe per R14's occupancy-insensitivity + work-conserving
//    makespan (4-block CUs carry -2.2% work each).
//  - (b) horizontal sums as a pure serial chain: a=pp+dpp1(pp);
//    b=a+dpp2(pp); Se=b+dpp3(e); c=b-e; So=c+dpp3(pp). Every DPP result
//    is single-use feeding one add -> GCNDPPCombine fuses to v_add_f32_dpp:
//    5 VALU/plane vs ~7 (old form's t=d1+d2 had two DPP consumers).
//    -10 instr/output row. Depth 3->4 acceptable at ~50% VALUBusy.
//  - Failure rule: > +0.5us regression -> revert to R15, declare roofline.

template <int CTRL>
__device__ __forceinline__ float dpp_sh(float v) {
    return __int_as_float(__builtin_amdgcn_update_dpp(
        0, __float_as_int(v), CTRL, 0xf, 0xf, true));
}

__device__ __forceinline__ float2 f2add(float2 a, float2 b) { return make_float2(a.x + b.x, a.y + b.y); }
__device__ __forceinline__ float2 f2sub(float2 a, float2 b) { return make_float2(a.x - b.x, a.y - b.y); }
__device__ __forceinline__ float2 f2mul(float2 a, float2 b) { return make_float2(a.x * b.x, a.y * b.y); }
__device__ __forceinline__ float2 f2fma(float2 a, float2 b, float2 c) {
    return make_float2(fmaf(a.x, b.x, c.x), fmaf(a.y, b.y, c.y));
}
__device__ __forceinline__ float2 f2fnma(float2 a, float2 b, float2 c) {  // c - a*b
    return make_float2(fmaf(-a.x, b.x, c.x), fmaf(-a.y, b.y, c.y));
}
__device__ __forceinline__ float2 f2fms(float2 a, float s, float2 c) {    // a*s - c
    return make_float2(fmaf(a.x, s, -c.x), fmaf(a.y, s, -c.y));
}
__device__ __forceinline__ float2 f2s(float s) { return make_float2(s, s); }

__global__ __launch_bounds__(BLOCK)
__attribute__((amdgpu_waves_per_eu(4, 4)))
void ssim_kernel(
    const float* __restrict__ X, const float* __restrict__ Y,
    const float* __restrict__ data_range, float* __restrict__ part)
{
    const int tid = threadIdx.x;
    const int b   = blockIdx.z;
    const int y0  = blockIdx.y * SROWS;

    const float* __restrict__ Xb = X + b * (IMH * IMW);
    const float* __restrict__ Yb = Y + b * (IMH * IMW);

    const int g   = tid >> 4;                 // DPP group 0..15
    const int j   = tid & 15;                 // lane within group
    const int ce  = g * GSTRIDE + 2 * j;      // lane's even column (global)
    const int cin = min(ce, IMW - 2);         // clamped, even -> 8B aligned
    const float2 vmask = make_float2(
        ((j <= 12) && (ce     < OW)) ? 1.f : 0.f,
        ((j <= 12) && (ce + 1 < OW)) ? 1.f : 0.f);

    const float L     = data_range[b];
    const float C1    = (0.01f * L) * (0.01f * L);
    const float C2    = (0.03f * L) * (0.03f * L);
    // scaled constants: SSIM ratio is invariant to the 1/49 normalization,
    // so work in "x49" units and fold 49^2 into C1/C2.
    const float C1q   = C1 * 2401.0f;          // C1 * 49^2
    const float C2q   = C2 * 2401.0f;          // C2 * 49^2
    const float covn  = 49.0f / 48.0f;
    const float c2cov = 2.0f * covn;

    // per-lane raw history of its 2 columns + running vertical sums
    float2 xh[7], yh[7];
    #pragma unroll
    for (int k = 0; k < 7; ++k) { xh[k] = f2s(0.f); yh[k] = f2s(0.f); }
    float2 V0 = f2s(0.f), V1 = f2s(0.f), V2 = f2s(0.f),
           V3 = f2s(0.f), V4 = f2s(0.f);
    float2 ls2 = f2s(0.f);

    // depth-2 explicit pipeline: rows r+1 and r+2 in flight
    float2 px[2], py[2];
    {
        const int r0 = y0;
        const int r1 = y0 + 1;                 // y0+1 <= 352+1 < 384 always
        px[0] = *(const float2*)(Xb + r0 * IMW + cin);
        py[0] = *(const float2*)(Yb + r0 * IMW + cin);
        px[1] = *(const float2*)(Xb + r1 * IMW + cin);
        py[1] = *(const float2*)(Yb + r1 * IMW + cin);
    }

    #pragma unroll
    for (int r = 0; r < INROWS; ++r) {
        const int slot = r & 1;                        // static after unroll
        const float2 x = px[slot], y = py[slot];
        if (r + 2 < INROWS) {                          // refill consumed slot
            const int ri = y0 + r + 2;                 // max 351+32=383, in-range
            px[slot] = *(const float2*)(Xb + ri * IMW + cin);
            py[slot] = *(const float2*)(Yb + ri * IMW + cin);
        }

        // vertical 7-row slide on both columns (pk-f32 eligible).
        // r<7: history is all zeros -> skip the subtract half (statically).
        const int ks = r % 7;                          // static after unroll
        if (r >= 7) {
            const float2 xo = xh[ks], yo = yh[ks];
            V0 = f2add(V0, f2sub(x, xo));
            V1 = f2add(V1, f2sub(y, yo));
            V2 = f2fma(x, x, V2);  V2 = f2fnma(xo, xo, V2);
            V3 = f2fma(x, y, V3);  V3 = f2fnma(xo, yo, V3);
            V4 = f2fma(y, y, V4);  V4 = f2fnma(yo, yo, V4);
        } else {
            V0 = f2add(V0, x);
            V1 = f2add(V1, y);
            V2 = f2fma(x, x, V2);
            V3 = f2fma(x, y, V3);
            V4 = f2fma(y, y, V4);
        }
        if (r + 7 < INROWS) {                          // slot read again?
            xh[ks] = x; yh[ks] = y;
        }

        // output row o = y0+r-6; exact tiling -> always valid, no OH mask.
        if (r >= 6) {
            // horizontal 7-window sums, serial DPP-fusable chain (5 ops/plane):
            //   a  = pp + pp(l+1)      [v_add_f32_dpp]
            //   bb = a  + pp(l+2)      [v_add_f32_dpp]
            //   Se = bb + e(l+3)       [v_add_f32_dpp]
            //   c  = bb - e
            //   So = c  + pp(l+3)      [v_add_f32_dpp]
            const float2 Vv[5] = {V0, V1, V2, V3, V4};
            float Se[5], So[5];
            #pragma unroll
            for (int p = 0; p < 5; ++p) {
                const float e   = Vv[p].x;
                const float o   = Vv[p].y;
                const float pp  = e + o;               // lane pair sum
                const float a   = pp + dpp_sh<0x101>(pp);
                const float bb  = a  + dpp_sh<0x102>(pp);
                Se[p] = bb + dpp_sh<0x103>(e);         // cols 2l..2l+6
                So[p] = (bb - e) + dpp_sh<0x103>(pp);  // cols 2l+1..2l+7
            }
            const float2 S0 = make_float2(Se[0], So[0]);
            const float2 S1 = make_float2(Se[1], So[1]);
            const float2 S2 = make_float2(Se[2], So[2]);
            const float2 S3 = make_float2(Se[3], So[3]);
            const float2 S4 = make_float2(Se[4], So[4]);

            // scaled SSIM: all 49^2 factors cancel in the ratio
            float2 P01 = f2mul(S0, S1);
            float2 Q0  = f2mul(S0, S0);
            float2 Q1  = f2mul(S1, S1);
            float2 N1  = f2fma(f2s(2.f), P01, f2s(C1q));
            float2 D1  = f2add(f2add(Q0, Q1), f2s(C1q));
            float2 T2  = f2fms(S2, 49.f, Q0);          // 49*S2 - S0^2
            float2 T3  = f2fms(S3, 49.f, P01);         // 49*S3 - S0*S1
            float2 T4  = f2fms(S4, 49.f, Q1);          // 49*S4 - S1^2
            float2 N2  = f2fma(f2s(c2cov), T3, f2s(C2q));
            float2 D2  = f2fma(f2s(covn), f2add(T2, T4), f2s(C2q));
            float2 num = f2mul(N1, N2);
            float2 den = f2mul(D1, D2);
            // one rcp for both columns: se = nx*dy/(dx*dy), so = ny*dx/(dx*dy)
            const float rdd = __builtin_amdgcn_rcpf(den.x * den.y);
            float2 s2 = make_float2(num.x * den.y * rdd,
                                    num.y * den.x * rdd);
            ls2 = f2fma(s2, vmask, ls2);
        }
    }

    float lsum = ls2.x + ls2.y;

    // ---- Block reduction: wave64 shuffle -> LDS -> one plain store/block ----
    __shared__ float red[BLOCK / 64];
    #pragma unroll
    for (int off = 32; off > 0; off >>= 1)
        lsum += __shfl_down(lsum, off, 64);
    if ((tid & 63) == 0) red[tid >> 6] = lsum;
    __syncthreads();
    if (tid == 0) {
        float bs = 0.f;
        #pragma unroll
        for (int k = 0; k < BLOCK / 64; ++k) bs += red[k];
        part[blockIdx.z * NSTRIP + blockIdx.y] = bs;   // poison-safe overwrite
    }
}

__global__ __launch_bounds__(256)
void finalize_kernel(const float* __restrict__ part, float* __restrict__ out)
{
    const int tid = threadIdx.x;
    // NBLOCKS = 896 = 224 threads x float4; lanes 224..255 contribute 0
    float s = 0.f;
    if (tid < NBLOCKS / 4) {
        float4 v = reinterpret_cast<const float4*>(part)[tid];
        s = (v.x + v.y) + (v.z + v.w);
    }
    #pragma unroll
    for (int off = 32; off > 0; off >>= 1)
        s += __shfl_down(s, off, 64);
    __shared__ float red[4];
    if ((tid & 63) == 0) red[tid >> 6] = s;
    __syncthreads();
    if (tid == 0) {
        float t = (red[0] + red[1]) + (red[2] + red[3]);
        out[0] = 1.0f - t * (1.0f / ((float)NB * (float)OH * (float)OW));
    }
}

extern "C" void kernel_launch(void* const* d_in, const int* in_sizes, int n_in,
                              void* d_out, int out_size, void* d_ws, size_t ws_size,
                              hipStream_t stream) {
    const float* X  = (const float*)d_in[0];
    const float* Y  = (const float*)d_in[1];
    const float* dr = (const float*)d_in[2];
    float* out  = (float*)d_out;
    float* part = (float*)d_ws;

    dim3 grid(1, NSTRIP, NB);   // 14 x 64 = 896 blocks
    dim3 block(BLOCK);          // 256 threads = 4 waves
    ssim_kernel<<<grid, block, 0, stream>>>(X, Y, dr, part);
    finalize_kernel<<<1, 256, 0, stream>>>(part, out);
}

// Round 8
// 106.021 us; speedup vs baseline: 1.0376x; 1.0376x over previous
//
#include <hip/hip_runtime.h>

#define IMH 384
#define IMW 384
#define OH 378
#define OW 378
#define NB 64
#define SROWS 24
#define INROWS 30          // SROWS + 6
#define NSTRIP 16          // 16*24 = 384 >= 378; last strip row-masked
#define NBLOCKS (NSTRIP * NB)   // 1024 blocks = 4/CU even (balanced residency)
#define BLOCK 256          // 4 waves = 16 DPP groups of 16 lanes
#define GSTRIDE 26         // output cols per group (13 lanes x 2 cols)

// Round 17: isolate the DPP-chain variable; geometry back to R15.
//  - R16 FAILED (+3.3us) and the cause is identified: 896 blocks = 3.5/CU
//    with full residency means half the CUs carry 4x33=132 row-iters vs
//    R15's even 4x30=120. With ALL blocks co-resident there is no tail
//    packing: makespan = max per-CU load. Balance per-CU work, not total
//    work. 24x16 (4/CU even) is the balanced optimum for 4-wave blocks.
//  - R16 also bundled the serial DPP chain (6 VALU/plane vs 7, all DPP
//    single-use -> GCNDPPCombine fuses every add) -- unattributed. This
//    round tests it alone on R15 geometry.
//  - Pre-committed: >=107 -> chain is regressive -> R15 verbatim + declare
//    effective floor next round.

template <int CTRL>
__device__ __forceinline__ float dpp_sh(float v) {
    return __int_as_float(__builtin_amdgcn_update_dpp(
        0, __float_as_int(v), CTRL, 0xf, 0xf, true));
}

__device__ __forceinline__ float2 f2add(float2 a, float2 b) { return make_float2(a.x + b.x, a.y + b.y); }
__device__ __forceinline__ float2 f2sub(float2 a, float2 b) { return make_float2(a.x - b.x, a.y - b.y); }
__device__ __forceinline__ float2 f2mul(float2 a, float2 b) { return make_float2(a.x * b.x, a.y * b.y); }
__device__ __forceinline__ float2 f2fma(float2 a, float2 b, float2 c) {
    return make_float2(fmaf(a.x, b.x, c.x), fmaf(a.y, b.y, c.y));
}
__device__ __forceinline__ float2 f2fnma(float2 a, float2 b, float2 c) {  // c - a*b
    return make_float2(fmaf(-a.x, b.x, c.x), fmaf(-a.y, b.y, c.y));
}
__device__ __forceinline__ float2 f2fms(float2 a, float s, float2 c) {    // a*s - c
    return make_float2(fmaf(a.x, s, -c.x), fmaf(a.y, s, -c.y));
}
__device__ __forceinline__ float2 f2s(float s) { return make_float2(s, s); }

__global__ __launch_bounds__(BLOCK)
__attribute__((amdgpu_waves_per_eu(4, 4)))
void ssim_kernel(
    const float* __restrict__ X, const float* __restrict__ Y,
    const float* __restrict__ data_range, float* __restrict__ part)
{
    const int tid = threadIdx.x;
    const int b   = blockIdx.z;
    const int y0  = blockIdx.y * SROWS;

    const float* __restrict__ Xb = X + b * (IMH * IMW);
    const float* __restrict__ Yb = Y + b * (IMH * IMW);

    const int g   = tid >> 4;                 // DPP group 0..15
    const int j   = tid & 15;                 // lane within group
    const int ce  = g * GSTRIDE + 2 * j;      // lane's even column (global)
    const int cin = min(ce, IMW - 2);         // clamped, even -> 8B aligned
    const float2 vmask = make_float2(
        ((j <= 12) && (ce     < OW)) ? 1.f : 0.f,
        ((j <= 12) && (ce + 1 < OW)) ? 1.f : 0.f);

    const float L     = data_range[b];
    const float C1    = (0.01f * L) * (0.01f * L);
    const float C2    = (0.03f * L) * (0.03f * L);
    // scaled constants: SSIM ratio is invariant to the 1/49 normalization,
    // so work in "x49" units and fold 49^2 into C1/C2.
    const float C1q   = C1 * 2401.0f;          // C1 * 49^2
    const float C2q   = C2 * 2401.0f;          // C2 * 49^2
    const float covn  = 49.0f / 48.0f;
    const float c2cov = 2.0f * covn;

    // per-lane raw history of its 2 columns + running vertical sums
    float2 xh[7], yh[7];
    #pragma unroll
    for (int k = 0; k < 7; ++k) { xh[k] = f2s(0.f); yh[k] = f2s(0.f); }
    float2 V0 = f2s(0.f), V1 = f2s(0.f), V2 = f2s(0.f),
           V3 = f2s(0.f), V4 = f2s(0.f);
    float2 ls2 = f2s(0.f);

    // depth-2 explicit pipeline: rows r+1 and r+2 in flight
    float2 px[2], py[2];
    {
        const int r0 = min(y0,     IMH - 1);
        const int r1 = min(y0 + 1, IMH - 1);
        px[0] = *(const float2*)(Xb + r0 * IMW + cin);
        py[0] = *(const float2*)(Yb + r0 * IMW + cin);
        px[1] = *(const float2*)(Xb + r1 * IMW + cin);
        py[1] = *(const float2*)(Yb + r1 * IMW + cin);
    }

    #pragma unroll
    for (int r = 0; r < INROWS; ++r) {
        const int slot = r & 1;                        // static after unroll
        const float2 x = px[slot], y = py[slot];
        if (r + 2 < INROWS) {                          // refill consumed slot
            const int ri = min(y0 + r + 2, IMH - 1);   // uniform row clamp
            px[slot] = *(const float2*)(Xb + ri * IMW + cin);
            py[slot] = *(const float2*)(Yb + ri * IMW + cin);
        }

        // vertical 7-row slide on both columns (pk-f32 eligible).
        // r<7: history is all zeros -> skip the subtract half (statically).
        const int ks = r % 7;                          // static after unroll
        if (r >= 7) {
            const float2 xo = xh[ks], yo = yh[ks];
            V0 = f2add(V0, f2sub(x, xo));
            V1 = f2add(V1, f2sub(y, yo));
            V2 = f2fma(x, x, V2);  V2 = f2fnma(xo, xo, V2);
            V3 = f2fma(x, y, V3);  V3 = f2fnma(xo, yo, V3);
            V4 = f2fma(y, y, V4);  V4 = f2fnma(yo, yo, V4);
        } else {
            V0 = f2add(V0, x);
            V1 = f2add(V1, y);
            V2 = f2fma(x, x, V2);
            V3 = f2fma(x, y, V3);
            V4 = f2fma(y, y, V4);
        }
        if (r + 7 < INROWS) {                          // slot read again?
            xh[ks] = x; yh[ks] = y;
        }

        // output row o = y0+r-6; last strip (y0=360) masks o >= OH.
        // condition is wave-uniform -> cheap scalar branch.
        if (r >= 6 && (y0 + r - 6) < OH) {
            // horizontal 7-window sums, serial DPP-fusable chain (6 ops/plane):
            //   pp = e + o
            //   a  = pp + pp(l+1)      [v_add_f32_dpp]
            //   bb = a  + pp(l+2)      [v_add_f32_dpp]
            //   Se = bb + e(l+3)       [v_add_f32_dpp]
            //   c  = bb - e
            //   So = c  + pp(l+3)      [v_add_f32_dpp]
            const float2 Vv[5] = {V0, V1, V2, V3, V4};
            float Se[5], So[5];
            #pragma unroll
            for (int p = 0; p < 5; ++p) {
                const float e   = Vv[p].x;
                const float o   = Vv[p].y;
                const float pp  = e + o;               // lane pair sum
                const float a   = pp + dpp_sh<0x101>(pp);
                const float bb  = a  + dpp_sh<0x102>(pp);
                Se[p] = bb + dpp_sh<0x103>(e);         // cols 2l..2l+6
                So[p] = (bb - e) + dpp_sh<0x103>(pp);  // cols 2l+1..2l+7
            }
            const float2 S0 = make_float2(Se[0], So[0]);
            const float2 S1 = make_float2(Se[1], So[1]);
            const float2 S2 = make_float2(Se[2], So[2]);
            const float2 S3 = make_float2(Se[3], So[3]);
            const float2 S4 = make_float2(Se[4], So[4]);

            // scaled SSIM: all 49^2 factors cancel in the ratio
            float2 P01 = f2mul(S0, S1);
            float2 Q0  = f2mul(S0, S0);
            float2 Q1  = f2mul(S1, S1);
            float2 N1  = f2fma(f2s(2.f), P01, f2s(C1q));
            float2 D1  = f2add(f2add(Q0, Q1), f2s(C1q));
            float2 T2  = f2fms(S2, 49.f, Q0);          // 49*S2 - S0^2
            float2 T3  = f2fms(S3, 49.f, P01);         // 49*S3 - S0*S1
            float2 T4  = f2fms(S4, 49.f, Q1);          // 49*S4 - S1^2
            float2 N2  = f2fma(f2s(c2cov), T3, f2s(C2q));
            float2 D2  = f2fma(f2s(covn), f2add(T2, T4), f2s(C2q));
            float2 num = f2mul(N1, N2);
            float2 den = f2mul(D1, D2);
            // one rcp for both columns: se = nx*dy/(dx*dy), so = ny*dx/(dx*dy)
            const float rdd = __builtin_amdgcn_rcpf(den.x * den.y);
            float2 s2 = make_float2(num.x * den.y * rdd,
                                    num.y * den.x * rdd);
            ls2 = f2fma(s2, vmask, ls2);
        }
    }

    float lsum = ls2.x + ls2.y;

    // ---- Block reduction: wave64 shuffle -> LDS -> one plain store/block ----
    __shared__ float red[BLOCK / 64];
    #pragma unroll
    for (int off = 32; off > 0; off >>= 1)
        lsum += __shfl_down(lsum, off, 64);
    if ((tid & 63) == 0) red[tid >> 6] = lsum;
    __syncthreads();
    if (tid == 0) {
        float bs = 0.f;
        #pragma unroll
        for (int k = 0; k < BLOCK / 64; ++k) bs += red[k];
        part[blockIdx.z * NSTRIP + blockIdx.y] = bs;   // poison-safe overwrite
    }
}

__global__ __launch_bounds__(256)
void finalize_kernel(const float* __restrict__ part, float* __restrict__ out)
{
    const int tid = threadIdx.x;
    // NBLOCKS = 1024 = 256 threads x float4
    float4 v = reinterpret_cast<const float4*>(part)[tid];
    float s = (v.x + v.y) + (v.z + v.w);
    #pragma unroll
    for (int off = 32; off > 0; off >>= 1)
        s += __shfl_down(s, off, 64);
    __shared__ float red[4];
    if ((tid & 63) == 0) red[tid >> 6] = s;
    __syncthreads();
    if (tid == 0) {
        float t = (red[0] + red[1]) + (red[2] + red[3]);
        out[0] = 1.0f - t * (1.0f / ((float)NB * (float)OH * (float)OW));
    }
}

extern "C" void kernel_launch(void* const* d_in, const int* in_sizes, int n_in,
                              void* d_out, int out_size, void* d_ws, size_t ws_size,
                              hipStream_t stream) {
    const float* X  = (const float*)d_in[0];
    const float* Y  = (const float*)d_in[1];
    const float* dr = (const float*)d_in[2];
    float* out  = (float*)d_out;
    float* part = (float*)d_ws;

    dim3 grid(1, NSTRIP, NB);   // 16 x 64 = 1024 blocks = 4/CU even
    dim3 block(BLOCK);          // 256 threads = 4 waves
    ssim_kernel<<<grid, block, 0, stream>>>(X, Y, dr, part);
    finalize_kernel<<<1, 256, 0, stream>>>(part, out);
}